// Round 9
// baseline (22414.473 us; speedup 1.0000x reference)
//
#include <hip/hip_runtime.h>
#include <stdint.h>

#define AGENT __HIP_MEMORY_SCOPE_AGENT
typedef unsigned long long u64;

// x[64][256][256] -> xT[t][iq][b][4]   (packed quads of input dim, batch-minor)
__global__ __launch_bounds__(256) void xpose_in(const float* __restrict__ x,
                                                float* __restrict__ xT) {
  const int t = blockIdx.x;
  const int b = threadIdx.x & 63;
  const int w = threadIdx.x >> 6;
  const float* xr = x + ((size_t)b * 256 + t) * 256;
  float* o = xT + (size_t)t * 64 * 256;
  for (int iq = w * 16; iq < w * 16 + 16; ++iq) {
    float4 v = *(const float4*)(xr + iq * 4);
    *(float4*)(o + ((size_t)iq * 64 + b) * 4) = v;
  }
}

// Pack [W;U] ([KT][4H], col cg) into wuT[cg][k] (transpose, coalesced both sides)
__global__ __launch_bounds__(256) void pack_wu(const float* __restrict__ W,
                                               const float* __restrict__ U,
                                               float* __restrict__ out,
                                               int DIN, int H) {
  __shared__ float tile[64][65];
  const int KT = DIN + H;
  const int c0 = blockIdx.x * 64;
  const int k0 = blockIdx.y * 64;
  const int tx = threadIdx.x & 63;
  const int ty = threadIdx.x >> 6;
  for (int r = ty; r < 64; r += 4) {
    const int k = k0 + r;
    tile[r][tx] = (k < DIN) ? W[(size_t)k * (4 * H) + c0 + tx]
                            : U[(size_t)(k - DIN) * (4 * H) + c0 + tx];
  }
  __syncthreads();
  for (int r = ty; r < 64; r += 4) {
    out[(size_t)(c0 + r) * KT + k0 + tx] = tile[tx][r];
  }
}

// Accumulate QW quads (this wave's K-slice) of src into acc[16] (c = g*4+jl).
// src: [quad][64][4] (per-lane float4). Weights from LDS: wL[c*KT+k] via
// wave-uniform ds_read_b128 (broadcast, conflict-free, zero global traffic).
// Activation loads chunk-double-buffered to hide L2/LLC latency.
// Register shape mirrors round 7 (proven spill-free at the 128-VGPR cap).
template <int QW, int CH, int KT>
__device__ __forceinline__ void accum4L(const float* __restrict__ src, int q0,
                                        int kof0, const float* __restrict__ wL,
                                        int lane, float acc[16]) {
  constexpr int NCH = QW / CH;
  float4 cur[CH], nxt[CH];
#pragma unroll
  for (int i = 0; i < CH; ++i)
    cur[i] = *(const float4*)(src + (size_t)(q0 + i) * 256 + lane * 4);
  for (int ch = 0; ch < NCH; ++ch) {
    const int qb = q0 + ch * CH;
    if (ch + 1 < NCH) {
#pragma unroll
      for (int i = 0; i < CH; ++i)
        nxt[i] = *(const float4*)(src + (size_t)(qb + CH + i) * 256 + lane * 4);
    }
#pragma unroll
    for (int i = 0; i < CH; ++i) {
      const int kof = kof0 + 4 * (qb + i);
      const float4 xv = cur[i];
#pragma unroll
      for (int c = 0; c < 16; ++c) {
        const float4 w = *(const float4*)(wL + (size_t)c * KT + kof);
        float& a = acc[c];
        a = fmaf(w.x, xv.x, a);
        a = fmaf(w.y, xv.y, a);
        a = fmaf(w.z, xv.z, a);
        a = fmaf(w.w, xv.w, a);
      }
    }
#pragma unroll
    for (int i = 0; i < CH; ++i) cur[i] = nxt[i];
  }
}

// One pipelined LSTM layer. 256-thread WG owns hidden quad wg (4 units,
// 16 weight rows LDS-resident). lane = batch; 4 waves split K 4-ways;
// wave jl also owns unit jl's gates (round-7 register shape: bz[4], scalar
// cst — spill-free). Flags agent-coherent; bulk h via cached loads
// (validated rounds 5/7). NWGP == producer's NWG (round-6 bug).
template <int DIN, int H, int NWG, int NWGP, bool FIN, bool XCOH>
__device__ __forceinline__ void layer_body(
    int wg, int tid, const float* __restrict__ xin, float* __restrict__ hseq,
    const float* __restrict__ wuT, const float* __restrict__ bias,
    float* __restrict__ dout, unsigned* __restrict__ selfF,
    unsigned* __restrict__ prevF, float* __restrict__ wL, float (*sZ)[16][64],
    float* sH) {
  constexpr int NQ2 = H / 4;
  constexpr int KT = DIN + H;
  constexpr int QW1 = DIN / 16;  // x-slice quads per wave
  constexpr int QW2 = H / 16;    // h-slice quads per wave
  constexpr int T = 256;
  static_assert(NWGP <= 128, "producer poll range must fit in tids 128..255");
  static_assert(QW1 % 4 == 0 && QW2 % 4 == 0, "chunking assumes 4|QW");

  const int lane = tid & 63;
  const int wv = tid >> 6;  // 0..3

  // ---- stage this WG's 16 weight rows into LDS (once) ----
  {
    constexpr int R4 = KT / 4;  // float4s per row
    for (int i = tid; i < 16 * R4; i += 256) {
      const int row = i / R4;
      const int k4 = i - row * R4;
      const int grow = (row >> 2) * H + wg * 4 + (row & 3);  // c = g*4+jl
      *(float4*)&wL[(size_t)row * KT + 4 * k4] =
          *(const float4*)(wuT + (size_t)grow * KT + 4 * k4);
    }
  }
  float bz[4];
#pragma unroll
  for (int g = 0; g < 4; ++g) bz[g] = bias[g * H + wg * 4 + wv];
  float cst = 0.f;
  __syncthreads();

  for (int t = 0; t < T; ++t) {
    float acc[16];
#pragma unroll
    for (int c = 0; c < 16; ++c) acc[c] = 0.f;

    if (!XCOH) {
      // layer 0: x static — overlap input projection with waiting for peers
      accum4L<QW1, 4, KT>(xin + (size_t)t * (DIN / 4) * 256, wv * QW1, 0, wL,
                          lane, acc);
    }
    // tids 0..NWG-1 poll self flags (t-1); 128..128+NWGP-1 poll producer (t)
    if (t > 0 && tid < NWG) {
      while (__hip_atomic_load(&selfF[(t - 1) * NWG + tid], __ATOMIC_RELAXED,
                               AGENT) == 0u) {
        __builtin_amdgcn_s_sleep(4);
      }
    }
    if (XCOH && tid >= 128 && tid < 128 + NWGP) {
      while (__hip_atomic_load(&prevF[t * NWGP + (tid - 128)], __ATOMIC_RELAXED,
                               AGENT) == 0u) {
        __builtin_amdgcn_s_sleep(4);
      }
    }
    __syncthreads();
    asm volatile("" ::: "memory");  // no compiler hoist of loads above polls

    if (XCOH) {
      accum4L<QW1, 4, KT>(xin + (size_t)t * (DIN / 4) * 256, wv * QW1, 0, wL,
                          lane, acc);
    }
    if (t > 0) {
      accum4L<QW2, 4, KT>(hseq + (size_t)(t - 1) * NQ2 * 256, wv * QW2, DIN,
                          wL, lane, acc);
    }

    // 4-way K-split reduction
#pragma unroll
    for (int c = 0; c < 16; ++c) sZ[wv][c][lane] = acc[c];
    __syncthreads();

    float z[4];
#pragma unroll
    for (int g = 0; g < 4; ++g) {
      z[g] = bz[g];
#pragma unroll
      for (int k = 0; k < 4; ++k) z[g] += sZ[k][g * 4 + wv][lane];
    }
    const float ig = 1.f / (1.f + __expf(-z[0]));
    const float fg = 1.f / (1.f + __expf(-z[1]));
    const float gg = FIN ? tanhf(z[2]) : fmaxf(z[2], 0.f);
    const float og = 1.f / (1.f + __expf(-z[3]));
    cst = fg * cst + ig * gg;
    const float ca = FIN ? tanhf(cst) : fmaxf(cst, 0.f);
    const float h = og * ca;
    sH[lane * 4 + wv] = h;  // [b][jl]
    if (FIN && t == T - 1) dout[(size_t)lane * H + wg * 4 + wv] = h;
    __syncthreads();

    // wave 0 publishes the WG's 1 KB h-quad (agent write-through), then signal
    if (wv == 0) {
      const float4 v = *(const float4*)&sH[lane * 4];
      float* hw = hseq + (size_t)t * NQ2 * 256 + (size_t)wg * 256 + lane * 4;
      const u64 lo = ((u64)__float_as_uint(v.y) << 32) | __float_as_uint(v.x);
      const u64 hi = ((u64)__float_as_uint(v.w) << 32) | __float_as_uint(v.z);
      __hip_atomic_store((u64*)hw, lo, __ATOMIC_RELAXED, AGENT);
      __hip_atomic_store((u64*)hw + 1, hi, __ATOMIC_RELAXED, AGENT);
      asm volatile("s_waitcnt vmcnt(0)" ::: "memory");
      if (tid == 0)
        __hip_atomic_store(&selfF[t * NWG + wg], 1u, __ATOMIC_RELAXED, AGENT);
    }
  }
}

__global__ __launch_bounds__(256, 2) void lstm_fused(
    const float* __restrict__ xT, float* __restrict__ h0,
    float* __restrict__ h1, float* __restrict__ h2, float* __restrict__ h3,
    float* __restrict__ h4, float* __restrict__ h5,
    const float* __restrict__ wuT0, const float* __restrict__ wuT1,
    const float* __restrict__ wuT2, const float* __restrict__ wuT3,
    const float* __restrict__ wuT4, const float* __restrict__ wuT5,
    const float* __restrict__ b0, const float* __restrict__ b1,
    const float* __restrict__ b2, const float* __restrict__ b3,
    const float* __restrict__ b4, const float* __restrict__ b5,
    float* __restrict__ dout, unsigned* __restrict__ f0,
    unsigned* __restrict__ f1, unsigned* __restrict__ f2,
    unsigned* __restrict__ f3, unsigned* __restrict__ f4,
    unsigned* __restrict__ f5) {
  __shared__ float wLDS[16 * 768];  // 48 KB: WG's 16 weight rows (max KT)
  __shared__ float sZ[4][16][64];   // 16 KB: 4-way K-split reduction
  __shared__ float sH[256];         // 1 KB: h staging
  const int b = blockIdx.x;
  const int tid = threadIdx.x;
  // heavy layers (L0, L4) first so they land one-per-CU
  if (b < 128) {
    layer_body<256, 512, 128, 0, false, false>(b, tid, xT, h0, wuT0, b0,
                                               nullptr, f0, nullptr, wLDS, sZ,
                                               sH);
  } else if (b < 256) {
    layer_body<256, 512, 128, 64, false, true>(b - 128, tid, h3, h4, wuT4, b4,
                                               nullptr, f4, f3, wLDS, sZ, sH);
  } else if (b < 320) {
    layer_body<512, 256, 64, 128, false, true>(b - 256, tid, h0, h1, wuT1, b1,
                                               nullptr, f1, f0, wLDS, sZ, sH);
  } else if (b < 384) {
    layer_body<64, 256, 64, 16, false, true>(b - 320, tid, h2, h3, wuT3, b3,
                                             nullptr, f3, f2, wLDS, sZ, sH);
  } else if (b < 448) {
    layer_body<512, 256, 64, 128, true, true>(b - 384, tid, h4, h5, wuT5, b5,
                                              dout, f5, f4, wLDS, sZ, sH);
  } else {
    layer_body<256, 64, 16, 64, false, true>(b - 448, tid, h1, h2, wuT2, b2,
                                             nullptr, f2, f1, wLDS, sZ, sH);
  }
}

extern "C" void kernel_launch(void* const* d_in, const int* in_sizes, int n_in,
                              void* d_out, int out_size, void* d_ws,
                              size_t ws_size, hipStream_t stream) {
  (void)in_sizes; (void)n_in; (void)out_size; (void)ws_size;
  const float* x = (const float*)d_in[0];
  const float* W[6];
  const float* U[6];
  const float* B[6];
  for (int l = 0; l < 6; ++l) {
    W[l] = (const float*)d_in[1 + 3 * l];
    U[l] = (const float*)d_in[2 + 3 * l];
    B[l] = (const float*)d_in[3 + 3 * l];
  }
  char* ws = (char*)d_ws;
  // flags: [T][NWG] per layer; NWG = 128,64,16,64,128,64
  unsigned* f0 = (unsigned*)ws;
  unsigned* f1 = f0 + 128 * 256;
  unsigned* f2 = f1 + 64 * 256;
  unsigned* f3 = f2 + 16 * 256;
  unsigned* f4 = f3 + 64 * 256;
  unsigned* f5 = f4 + 128 * 256;
  float* wuT0 = (float*)(ws + (1u << 20));
  float* wuT1 = wuT0 + (size_t)2048 * 768;
  float* wuT2 = wuT1 + (size_t)1024 * 768;
  float* wuT3 = wuT2 + (size_t)256 * 320;
  float* wuT4 = wuT3 + (size_t)1024 * 320;
  float* wuT5 = wuT4 + (size_t)2048 * 768;
  float* xT = (float*)(ws + (22u << 20));   // 16 MB
  float* h0 = (float*)(ws + (38u << 20));   // 32 MB
  float* h1 = (float*)(ws + (70u << 20));   // 16 MB
  float* h2 = (float*)(ws + (86u << 20));   // 4 MB
  float* h3 = (float*)(ws + (90u << 20));   // 16 MB
  float* h4 = (float*)(ws + (106u << 20));  // 32 MB
  float* h5 = (float*)(ws + (138u << 20));  // 16 MB (full T, no ring)

  hipMemsetAsync(f0, 0, 464 * 256 * sizeof(unsigned), stream);
  xpose_in<<<256, 256, 0, stream>>>(x, xT);
  pack_wu<<<dim3(32, 12), 256, 0, stream>>>(W[0], U[0], wuT0, 256, 512);
  pack_wu<<<dim3(16, 12), 256, 0, stream>>>(W[1], U[1], wuT1, 512, 256);
  pack_wu<<<dim3(4, 5), 256, 0, stream>>>(W[2], U[2], wuT2, 256, 64);
  pack_wu<<<dim3(16, 5), 256, 0, stream>>>(W[3], U[3], wuT3, 64, 256);
  pack_wu<<<dim3(32, 12), 256, 0, stream>>>(W[4], U[4], wuT4, 256, 512);
  pack_wu<<<dim3(16, 12), 256, 0, stream>>>(W[5], U[5], wuT5, 512, 256);

  lstm_fused<<<464, 256, 0, stream>>>(xT, h0, h1, h2, h3, h4, h5, wuT0, wuT1,
                                      wuT2, wuT3, wuT4, wuT5, B[0], B[1], B[2],
                                      B[3], B[4], B[5], (float*)d_out, f0, f1,
                                      f2, f3, f4, f5);
}

// Round 10
// 17915.988 us; speedup vs baseline: 1.2511x; 1.2511x over previous
//
#include <hip/hip_runtime.h>
#include <stdint.h>

#define AGENT __HIP_MEMORY_SCOPE_AGENT
typedef unsigned long long u64;

// x[64][256][256] -> xT[t][iq][b][4]   (packed quads of input dim, batch-minor)
__global__ __launch_bounds__(256) void xpose_in(const float* __restrict__ x,
                                                float* __restrict__ xT) {
  const int t = blockIdx.x;
  const int b = threadIdx.x & 63;
  const int w = threadIdx.x >> 6;
  const float* xr = x + ((size_t)b * 256 + t) * 256;
  float* o = xT + (size_t)t * 64 * 256;
  for (int iq = w * 16; iq < w * 16 + 16; ++iq) {
    float4 v = *(const float4*)(xr + iq * 4);
    *(float4*)(o + ((size_t)iq * 64 + b) * 4) = v;
  }
}

// Pack [W;U] ([KT][4H], col cg) into wuT[cg][k] (transpose, coalesced both sides)
__global__ __launch_bounds__(256) void pack_wu(const float* __restrict__ W,
                                               const float* __restrict__ U,
                                               float* __restrict__ out,
                                               int DIN, int H) {
  __shared__ float tile[64][65];
  const int KT = DIN + H;
  const int c0 = blockIdx.x * 64;
  const int k0 = blockIdx.y * 64;
  const int tx = threadIdx.x & 63;
  const int ty = threadIdx.x >> 6;
  for (int r = ty; r < 64; r += 4) {
    const int k = k0 + r;
    tile[r][tx] = (k < DIN) ? W[(size_t)k * (4 * H) + c0 + tx]
                            : U[(size_t)(k - DIN) * (4 * H) + c0 + tx];
  }
  __syncthreads();
  for (int r = ty; r < 64; r += 4) {
    out[(size_t)(c0 + r) * KT + k0 + tx] = tile[tx][r];
  }
}

// Accumulate QW quads (this wave's K-slice) of src into acc[16] (c = g*4+jl).
// src: [quad][64][4]. bg[g] = weight row base for gate g (unit jl at +jl*KT).
// Plain cached loads (L2 dedups cross-WG broadcast); chunk double-buffered.
// Round-7 register shape — proven spill-free (WRITE_SIZE ~1.3 GB @128 VGPR).
template <int QW, int CH, int KT>
__device__ __forceinline__ void accum4(const float* __restrict__ src, int q0,
                                       int kof0, const float* const bg[4],
                                       int lane, float acc[16]) {
  constexpr int NCH = QW / CH;
  float4 cur[CH], nxt[CH];
#pragma unroll
  for (int i = 0; i < CH; ++i)
    cur[i] = *(const float4*)(src + (size_t)(q0 + i) * 256 + lane * 4);
  for (int ch = 0; ch < NCH; ++ch) {
    const int qb = q0 + ch * CH;
    if (ch + 1 < NCH) {
#pragma unroll
      for (int i = 0; i < CH; ++i)
        nxt[i] = *(const float4*)(src + (size_t)(qb + CH + i) * 256 + lane * 4);
    }
#pragma unroll
    for (int i = 0; i < CH; ++i) {
      const int kof = kof0 + 4 * (qb + i);
      const float4 xv = cur[i];
#pragma unroll
      for (int g = 0; g < 4; ++g) {
#pragma unroll
        for (int jl = 0; jl < 4; ++jl) {
          const float4 w = *(const float4*)(bg[g] + (size_t)jl * KT + kof);
          float& a = acc[g * 4 + jl];
          a = fmaf(w.x, xv.x, a);
          a = fmaf(w.y, xv.y, a);
          a = fmaf(w.z, xv.z, a);
          a = fmaf(w.w, xv.w, a);
        }
      }
    }
#pragma unroll
    for (int i = 0; i < CH; ++i) cur[i] = nxt[i];
  }
}

// Dedicated per-layer aggregator: one wave gathers this layer's NWG per-WG
// flags for tick t, then publishes a single monotonic epoch word (= ticks
// completed). Consumers poll ONLY the epoch word (1 lane, 1 line).
template <int NWG>
__device__ __forceinline__ void agg_body(unsigned* __restrict__ flg,
                                         unsigned* __restrict__ ep) {
  const int tid = threadIdx.x;
  if (tid >= 64) return;  // single wave
  for (int t = 0; t < 256; ++t) {
    unsigned* base = flg + (size_t)t * NWG;
    if (NWG <= 64) {
      if (tid < NWG) {
        while (__hip_atomic_load(base + tid, __ATOMIC_RELAXED, AGENT) == 0u)
          __builtin_amdgcn_s_sleep(1);
      }
    } else {
      while (__hip_atomic_load(base + tid, __ATOMIC_RELAXED, AGENT) == 0u)
        __builtin_amdgcn_s_sleep(1);
      while (__hip_atomic_load(base + 64 + tid, __ATOMIC_RELAXED, AGENT) == 0u)
        __builtin_amdgcn_s_sleep(1);
    }
    // all lanes converged => all NWG flags observed; drain, then publish
    asm volatile("s_waitcnt vmcnt(0)" ::: "memory");
    if (tid == 0)
      __hip_atomic_store(ep, (unsigned)(t + 1), __ATOMIC_RELAXED, AGENT);
  }
}

// One pipelined LSTM layer. 256-thread WG owns hidden quad wg (4 units).
// lane = batch; 4 waves split K 4-ways; wave jl owns unit jl's gates.
// Sync: per-WG flags -> layer aggregator -> single epoch word. Workers poll
// one word with one lane each (selfE >= t, prevE >= t+1). Bulk h via cached
// loads (validated rounds 5/7); h publish via agent write-through atomics.
template <int DIN, int H, int NWG, bool FIN, bool XCOH>
__device__ __forceinline__ void layer_body(
    int wg, int tid, const float* __restrict__ xin, float* __restrict__ hseq,
    const float* __restrict__ wuT, const float* __restrict__ bias,
    float* __restrict__ dout, unsigned* __restrict__ selfF,
    unsigned* __restrict__ selfE, unsigned* __restrict__ prevE,
    float (*sZ)[16][64], float* sH) {
  constexpr int NQ2 = H / 4;
  constexpr int KT = DIN + H;
  constexpr int QW1 = DIN / 16;  // x-slice quads per wave
  constexpr int QW2 = H / 16;    // h-slice quads per wave
  constexpr int T = 256;
  static_assert(QW1 % 4 == 0 && QW2 % 4 == 0, "chunking assumes 4|QW");

  const int lane = tid & 63;
  const int wv = tid >> 6;  // 0..3

  const float* bg[4];
#pragma unroll
  for (int g = 0; g < 4; ++g) bg[g] = wuT + ((size_t)(g * H + wg * 4)) * KT;

  float bz[4];
#pragma unroll
  for (int g = 0; g < 4; ++g) bz[g] = bias[g * H + wg * 4 + wv];

  float cst = 0.f;

  for (int t = 0; t < T; ++t) {
    float acc[16];
#pragma unroll
    for (int c = 0; c < 16; ++c) acc[c] = 0.f;

    if (!XCOH) {
      // layer 0: x static — overlap input projection with waiting for peers
      accum4<QW1, 4, KT>(xin + (size_t)t * (DIN / 4) * 256, wv * QW1, 0, bg,
                         lane, acc);
    }
    // single-lane epoch polls: tid 0 -> own layer (t-1 done); tid 64 -> prev
    if (t > 0 && tid == 0) {
      while (__hip_atomic_load(selfE, __ATOMIC_RELAXED, AGENT) < (unsigned)t)
        __builtin_amdgcn_s_sleep(2);
    }
    if (XCOH && tid == 64) {
      while (__hip_atomic_load(prevE, __ATOMIC_RELAXED, AGENT) <
             (unsigned)(t + 1))
        __builtin_amdgcn_s_sleep(2);
    }
    __syncthreads();
    asm volatile("" ::: "memory");  // no compiler hoist of loads above polls

    if (XCOH) {
      accum4<QW1, 4, KT>(xin + (size_t)t * (DIN / 4) * 256, wv * QW1, 0, bg,
                         lane, acc);
    }
    if (t > 0) {
      accum4<QW2, 4, KT>(hseq + (size_t)(t - 1) * NQ2 * 256, wv * QW2, DIN, bg,
                         lane, acc);
    }

    // 4-way K-split reduction
#pragma unroll
    for (int c = 0; c < 16; ++c) sZ[wv][c][lane] = acc[c];
    __syncthreads();

    float z[4];
#pragma unroll
    for (int g = 0; g < 4; ++g) {
      z[g] = bz[g];
#pragma unroll
      for (int k = 0; k < 4; ++k) z[g] += sZ[k][g * 4 + wv][lane];
    }
    const float ig = 1.f / (1.f + __expf(-z[0]));
    const float fg = 1.f / (1.f + __expf(-z[1]));
    const float gg = FIN ? tanhf(z[2]) : fmaxf(z[2], 0.f);
    const float og = 1.f / (1.f + __expf(-z[3]));
    cst = fg * cst + ig * gg;
    const float ca = FIN ? tanhf(cst) : fmaxf(cst, 0.f);
    const float h = og * ca;
    sH[lane * 4 + wv] = h;  // [b][jl]
    if (FIN && t == T - 1) dout[(size_t)lane * H + wg * 4 + wv] = h;
    __syncthreads();

    // wave 0 publishes the WG's 1 KB h-quad (agent write-through), then signal
    if (wv == 0) {
      const float4 v = *(const float4*)&sH[lane * 4];
      float* hw = hseq + (size_t)t * NQ2 * 256 + (size_t)wg * 256 + lane * 4;
      const u64 lo = ((u64)__float_as_uint(v.y) << 32) | __float_as_uint(v.x);
      const u64 hi = ((u64)__float_as_uint(v.w) << 32) | __float_as_uint(v.z);
      __hip_atomic_store((u64*)hw, lo, __ATOMIC_RELAXED, AGENT);
      __hip_atomic_store((u64*)hw + 1, hi, __ATOMIC_RELAXED, AGENT);
      asm volatile("s_waitcnt vmcnt(0)" ::: "memory");
      if (tid == 0)
        __hip_atomic_store(&selfF[t * NWG + wg], 1u, __ATOMIC_RELAXED, AGENT);
    }
  }
}

__global__ __launch_bounds__(256, 2) void lstm_fused(
    const float* __restrict__ xT, float* __restrict__ h0,
    float* __restrict__ h1, float* __restrict__ h2, float* __restrict__ h3,
    float* __restrict__ h4, float* __restrict__ h5,
    const float* __restrict__ wuT0, const float* __restrict__ wuT1,
    const float* __restrict__ wuT2, const float* __restrict__ wuT3,
    const float* __restrict__ wuT4, const float* __restrict__ wuT5,
    const float* __restrict__ b0, const float* __restrict__ b1,
    const float* __restrict__ b2, const float* __restrict__ b3,
    const float* __restrict__ b4, const float* __restrict__ b5,
    float* __restrict__ dout, unsigned* __restrict__ f0,
    unsigned* __restrict__ f1, unsigned* __restrict__ f2,
    unsigned* __restrict__ f3, unsigned* __restrict__ f4,
    unsigned* __restrict__ f5, unsigned* __restrict__ eps) {
  __shared__ float sZ[4][16][64];  // 16 KB
  __shared__ float sH[256];        // 1 KB
  const int b = blockIdx.x;
  const int tid = threadIdx.x;
  // heavy layers (L0, L4) first so they land one-per-CU; aggregators last
  if (b < 128) {
    layer_body<256, 512, 128, false, false>(b, tid, xT, h0, wuT0, b0, nullptr,
                                            f0, eps + 0, nullptr, sZ, sH);
  } else if (b < 256) {
    layer_body<256, 512, 128, false, true>(b - 128, tid, h3, h4, wuT4, b4,
                                           nullptr, f4, eps + 4, eps + 3, sZ,
                                           sH);
  } else if (b < 320) {
    layer_body<512, 256, 64, false, true>(b - 256, tid, h0, h1, wuT1, b1,
                                          nullptr, f1, eps + 1, eps + 0, sZ,
                                          sH);
  } else if (b < 384) {
    layer_body<64, 256, 64, false, true>(b - 320, tid, h2, h3, wuT3, b3,
                                         nullptr, f3, eps + 3, eps + 2, sZ, sH);
  } else if (b < 448) {
    layer_body<512, 256, 64, true, true>(b - 384, tid, h4, h5, wuT5, b5, dout,
                                         f5, eps + 5, eps + 4, sZ, sH);
  } else if (b < 464) {
    layer_body<256, 64, 16, false, true>(b - 448, tid, h1, h2, wuT2, b2,
                                         nullptr, f2, eps + 2, eps + 1, sZ, sH);
  } else {
    const int l = b - 464;
    if (l == 0) agg_body<128>(f0, eps + 0);
    else if (l == 1) agg_body<64>(f1, eps + 1);
    else if (l == 2) agg_body<16>(f2, eps + 2);
    else if (l == 3) agg_body<64>(f3, eps + 3);
    else if (l == 4) agg_body<128>(f4, eps + 4);
    else agg_body<64>(f5, eps + 5);
  }
}

extern "C" void kernel_launch(void* const* d_in, const int* in_sizes, int n_in,
                              void* d_out, int out_size, void* d_ws,
                              size_t ws_size, hipStream_t stream) {
  (void)in_sizes; (void)n_in; (void)out_size; (void)ws_size;
  const float* x = (const float*)d_in[0];
  const float* W[6];
  const float* U[6];
  const float* B[6];
  for (int l = 0; l < 6; ++l) {
    W[l] = (const float*)d_in[1 + 3 * l];
    U[l] = (const float*)d_in[2 + 3 * l];
    B[l] = (const float*)d_in[3 + 3 * l];
  }
  char* ws = (char*)d_ws;
  // flags: [T][NWG] per layer; NWG = 128,64,16,64,128,64; then 6 epochs
  unsigned* f0 = (unsigned*)ws;
  unsigned* f1 = f0 + 128 * 256;
  unsigned* f2 = f1 + 64 * 256;
  unsigned* f3 = f2 + 16 * 256;
  unsigned* f4 = f3 + 64 * 256;
  unsigned* f5 = f4 + 128 * 256;
  unsigned* eps = f0 + 464 * 256;
  float* wuT0 = (float*)(ws + (1u << 20));
  float* wuT1 = wuT0 + (size_t)2048 * 768;
  float* wuT2 = wuT1 + (size_t)1024 * 768;
  float* wuT3 = wuT2 + (size_t)256 * 320;
  float* wuT4 = wuT3 + (size_t)1024 * 320;
  float* wuT5 = wuT4 + (size_t)2048 * 768;
  float* xT = (float*)(ws + (22u << 20));   // 16 MB
  float* h0 = (float*)(ws + (38u << 20));   // 32 MB
  float* h1 = (float*)(ws + (70u << 20));   // 16 MB
  float* h2 = (float*)(ws + (86u << 20));   // 4 MB
  float* h3 = (float*)(ws + (90u << 20));   // 16 MB
  float* h4 = (float*)(ws + (106u << 20));  // 32 MB
  float* h5 = (float*)(ws + (138u << 20));  // 16 MB (full T, no ring)

  hipMemsetAsync(f0, 0, (464 * 256 + 8) * sizeof(unsigned), stream);
  xpose_in<<<256, 256, 0, stream>>>(x, xT);
  pack_wu<<<dim3(32, 12), 256, 0, stream>>>(W[0], U[0], wuT0, 256, 512);
  pack_wu<<<dim3(16, 12), 256, 0, stream>>>(W[1], U[1], wuT1, 512, 256);
  pack_wu<<<dim3(4, 5), 256, 0, stream>>>(W[2], U[2], wuT2, 256, 64);
  pack_wu<<<dim3(16, 5), 256, 0, stream>>>(W[3], U[3], wuT3, 64, 256);
  pack_wu<<<dim3(32, 12), 256, 0, stream>>>(W[4], U[4], wuT4, 256, 512);
  pack_wu<<<dim3(16, 12), 256, 0, stream>>>(W[5], U[5], wuT5, 512, 256);

  lstm_fused<<<470, 256, 0, stream>>>(xT, h0, h1, h2, h3, h4, h5, wuT0, wuT1,
                                      wuT2, wuT3, wuT4, wuT5, B[0], B[1], B[2],
                                      B[3], B[4], B[5], (float*)d_out, f0, f1,
                                      f2, f3, f4, f5, eps);
}

// Round 11
// 5719.069 us; speedup vs baseline: 3.9193x; 3.1327x over previous
//
#include <hip/hip_runtime.h>
#include <stdint.h>

#define AGENT __HIP_MEMORY_SCOPE_AGENT
typedef unsigned long long u64;

// x[64][256][256] -> xT[t][iq][b][4]   (packed quads of input dim, batch-minor)
__global__ __launch_bounds__(256) void xpose_in(const float* __restrict__ x,
                                                float* __restrict__ xT) {
  const int t = blockIdx.x;
  const int b = threadIdx.x & 63;
  const int w = threadIdx.x >> 6;
  const float* xr = x + ((size_t)b * 256 + t) * 256;
  float* o = xT + (size_t)t * 64 * 256;
  for (int iq = w * 16; iq < w * 16 + 16; ++iq) {
    float4 v = *(const float4*)(xr + iq * 4);
    *(float4*)(o + ((size_t)iq * 64 + b) * 4) = v;
  }
}

// Pack [W;U] ([KT][4H], col cg) into wuT[cg][k] (transpose, coalesced both sides)
__global__ __launch_bounds__(256) void pack_wu(const float* __restrict__ W,
                                               const float* __restrict__ U,
                                               float* __restrict__ out,
                                               int DIN, int H) {
  __shared__ float tile[64][65];
  const int KT = DIN + H;
  const int c0 = blockIdx.x * 64;
  const int k0 = blockIdx.y * 64;
  const int tx = threadIdx.x & 63;
  const int ty = threadIdx.x >> 6;
  for (int r = ty; r < 64; r += 4) {
    const int k = k0 + r;
    tile[r][tx] = (k < DIN) ? W[(size_t)k * (4 * H) + c0 + tx]
                            : U[(size_t)(k - DIN) * (4 * H) + c0 + tx];
  }
  __syncthreads();
  for (int r = ty; r < 64; r += 4) {
    out[(size_t)(c0 + r) * KT + k0 + tx] = tile[tx][r];
  }
}

// Accumulate QW quads (this wave's K-slice) of src into acc[16] (c = g*4+jl).
// src: [quad][64][4]. Weights LDS-resident: wL[c*KT + k], read as wave-uniform
// ds_read_b128 (broadcast, conflict-free, ZERO per-tick global weight traffic).
// ANTI-SPILL (rounds 8/9 lesson): columns processed in blocks of 4 with a
// sched_barrier(0) after each block so at most ~4 weight float4s are live;
// activation prefetch depth CH=2. Keeps total live regs < the 128-VGPR cap
// forced by the mandatory 2-blocks/CU co-residency.
template <int QW, int CH, int KT>
__device__ __forceinline__ void accum4L(const float* __restrict__ src, int q0,
                                        int kof0, const float* __restrict__ wL,
                                        int lane, float acc[16]) {
  constexpr int NCH = QW / CH;
  float4 cur[CH], nxt[CH];
#pragma unroll
  for (int i = 0; i < CH; ++i)
    cur[i] = *(const float4*)(src + (size_t)(q0 + i) * 256 + lane * 4);
  for (int ch = 0; ch < NCH; ++ch) {
    const int qb = q0 + ch * CH;
    if (ch + 1 < NCH) {
#pragma unroll
      for (int i = 0; i < CH; ++i)
        nxt[i] = *(const float4*)(src + (size_t)(qb + CH + i) * 256 + lane * 4);
    }
#pragma unroll
    for (int i = 0; i < CH; ++i) {
      const int kof = kof0 + 4 * (qb + i);
      const float4 xv = cur[i];
#pragma unroll
      for (int cb = 0; cb < 4; ++cb) {
        const float4 w0 = *(const float4*)(wL + (size_t)(cb * 4 + 0) * KT + kof);
        const float4 w1 = *(const float4*)(wL + (size_t)(cb * 4 + 1) * KT + kof);
        const float4 w2 = *(const float4*)(wL + (size_t)(cb * 4 + 2) * KT + kof);
        const float4 w3 = *(const float4*)(wL + (size_t)(cb * 4 + 3) * KT + kof);
        float& a0 = acc[cb * 4 + 0];
        float& a1 = acc[cb * 4 + 1];
        float& a2 = acc[cb * 4 + 2];
        float& a3 = acc[cb * 4 + 3];
        a0 = fmaf(w0.x, xv.x, a0); a0 = fmaf(w0.y, xv.y, a0);
        a0 = fmaf(w0.z, xv.z, a0); a0 = fmaf(w0.w, xv.w, a0);
        a1 = fmaf(w1.x, xv.x, a1); a1 = fmaf(w1.y, xv.y, a1);
        a1 = fmaf(w1.z, xv.z, a1); a1 = fmaf(w1.w, xv.w, a1);
        a2 = fmaf(w2.x, xv.x, a2); a2 = fmaf(w2.y, xv.y, a2);
        a2 = fmaf(w2.z, xv.z, a2); a2 = fmaf(w2.w, xv.w, a2);
        a3 = fmaf(w3.x, xv.x, a3); a3 = fmaf(w3.y, xv.y, a3);
        a3 = fmaf(w3.z, xv.z, a3); a3 = fmaf(w3.w, xv.w, a3);
        __builtin_amdgcn_sched_barrier(0);  // cap weight live-range (no spill)
      }
    }
#pragma unroll
    for (int i = 0; i < CH; ++i) cur[i] = nxt[i];
  }
}

// Dedicated per-layer aggregator: one wave gathers this layer's NWG per-WG
// flags for tick t, then publishes a single monotonic epoch word (= ticks
// completed). Consumers poll ONLY the epoch word (1 lane, 1 line).
template <int NWG>
__device__ __forceinline__ void agg_body(unsigned* __restrict__ flg,
                                         unsigned* __restrict__ ep) {
  const int tid = threadIdx.x;
  if (tid >= 64) return;  // single wave
  for (int t = 0; t < 256; ++t) {
    unsigned* base = flg + (size_t)t * NWG;
    if (NWG <= 64) {
      if (tid < NWG) {
        while (__hip_atomic_load(base + tid, __ATOMIC_RELAXED, AGENT) == 0u)
          __builtin_amdgcn_s_sleep(1);
      }
    } else {
      while (__hip_atomic_load(base + tid, __ATOMIC_RELAXED, AGENT) == 0u)
        __builtin_amdgcn_s_sleep(1);
      while (__hip_atomic_load(base + 64 + tid, __ATOMIC_RELAXED, AGENT) == 0u)
        __builtin_amdgcn_s_sleep(1);
    }
    asm volatile("s_waitcnt vmcnt(0)" ::: "memory");
    if (tid == 0)
      __hip_atomic_store(ep, (unsigned)(t + 1), __ATOMIC_RELAXED, AGENT);
  }
}

// One pipelined LSTM layer. 256-thread WG owns hidden quad wg (4 units);
// its 16 weight rows are staged ONCE into LDS. lane = batch; 4 waves split K
// 4-ways; wave jl owns unit jl's gates. Sync: per-WG flags -> aggregator ->
// epoch word; workers poll one word with one lane. Bulk h via cached loads.
template <int DIN, int H, int NWG, bool FIN, bool XCOH>
__device__ __forceinline__ void layer_body(
    int wg, int tid, const float* __restrict__ xin, float* __restrict__ hseq,
    const float* __restrict__ wuT, const float* __restrict__ bias,
    float* __restrict__ dout, unsigned* __restrict__ selfF,
    unsigned* __restrict__ selfE, unsigned* __restrict__ prevE,
    float* __restrict__ wL, float (*sZ)[16][64], float* sH) {
  constexpr int NQ2 = H / 4;
  constexpr int KT = DIN + H;
  constexpr int QW1 = DIN / 16;  // x-slice quads per wave
  constexpr int QW2 = H / 16;    // h-slice quads per wave
  constexpr int T = 256;
  static_assert(QW1 % 2 == 0 && QW2 % 2 == 0, "chunking assumes 2|QW");

  const int lane = tid & 63;
  const int wv = tid >> 6;  // 0..3

  // ---- stage this WG's 16 weight rows into LDS (once) ----
  {
    constexpr int R4 = KT / 4;  // float4s per row
    for (int i = tid; i < 16 * R4; i += 256) {
      const int row = i / R4;
      const int k4 = i - row * R4;
      const int grow = (row >> 2) * H + wg * 4 + (row & 3);  // c = g*4+jl
      *(float4*)&wL[(size_t)row * KT + 4 * k4] =
          *(const float4*)(wuT + (size_t)grow * KT + 4 * k4);
    }
  }
  float bz[4];
#pragma unroll
  for (int g = 0; g < 4; ++g) bz[g] = bias[g * H + wg * 4 + wv];
  float cst = 0.f;
  __syncthreads();

  for (int t = 0; t < T; ++t) {
    float acc[16];
#pragma unroll
    for (int c = 0; c < 16; ++c) acc[c] = 0.f;

    if (!XCOH) {
      // layer 0: x static — overlap input projection with waiting for peers
      accum4L<QW1, 2, KT>(xin + (size_t)t * (DIN / 4) * 256, wv * QW1, 0, wL,
                          lane, acc);
    }
    // single-lane epoch polls: tid 0 -> own layer (t-1 done); tid 64 -> prev
    if (t > 0 && tid == 0) {
      while (__hip_atomic_load(selfE, __ATOMIC_RELAXED, AGENT) < (unsigned)t)
        __builtin_amdgcn_s_sleep(2);
    }
    if (XCOH && tid == 64) {
      while (__hip_atomic_load(prevE, __ATOMIC_RELAXED, AGENT) <
             (unsigned)(t + 1))
        __builtin_amdgcn_s_sleep(2);
    }
    __syncthreads();
    asm volatile("" ::: "memory");  // no compiler hoist of loads above polls

    if (XCOH) {
      accum4L<QW1, 2, KT>(xin + (size_t)t * (DIN / 4) * 256, wv * QW1, 0, wL,
                          lane, acc);
    }
    if (t > 0) {
      accum4L<QW2, 2, KT>(hseq + (size_t)(t - 1) * NQ2 * 256, wv * QW2, DIN,
                          wL, lane, acc);
    }

    // 4-way K-split reduction
#pragma unroll
    for (int c = 0; c < 16; ++c) sZ[wv][c][lane] = acc[c];
    __syncthreads();

    float z[4];
#pragma unroll
    for (int g = 0; g < 4; ++g) {
      z[g] = bz[g];
#pragma unroll
      for (int k = 0; k < 4; ++k) z[g] += sZ[k][g * 4 + wv][lane];
    }
    const float ig = 1.f / (1.f + __expf(-z[0]));
    const float fg = 1.f / (1.f + __expf(-z[1]));
    const float gg = FIN ? tanhf(z[2]) : fmaxf(z[2], 0.f);
    const float og = 1.f / (1.f + __expf(-z[3]));
    cst = fg * cst + ig * gg;
    const float ca = FIN ? tanhf(cst) : fmaxf(cst, 0.f);
    const float h = og * ca;
    sH[lane * 4 + wv] = h;  // [b][jl]
    if (FIN && t == T - 1) dout[(size_t)lane * H + wg * 4 + wv] = h;
    __syncthreads();

    // wave 0 publishes the WG's 1 KB h-quad (agent write-through), then signal
    if (wv == 0) {
      const float4 v = *(const float4*)&sH[lane * 4];
      float* hw = hseq + (size_t)t * NQ2 * 256 + (size_t)wg * 256 + lane * 4;
      const u64 lo = ((u64)__float_as_uint(v.y) << 32) | __float_as_uint(v.x);
      const u64 hi = ((u64)__float_as_uint(v.w) << 32) | __float_as_uint(v.z);
      __hip_atomic_store((u64*)hw, lo, __ATOMIC_RELAXED, AGENT);
      __hip_atomic_store((u64*)hw + 1, hi, __ATOMIC_RELAXED, AGENT);
      asm volatile("s_waitcnt vmcnt(0)" ::: "memory");
      if (tid == 0)
        __hip_atomic_store(&selfF[t * NWG + wg], 1u, __ATOMIC_RELAXED, AGENT);
    }
  }
}

__global__ __launch_bounds__(256, 2) void lstm_fused(
    const float* __restrict__ xT, float* __restrict__ h0,
    float* __restrict__ h1, float* __restrict__ h2, float* __restrict__ h3,
    float* __restrict__ h4, float* __restrict__ h5,
    const float* __restrict__ wuT0, const float* __restrict__ wuT1,
    const float* __restrict__ wuT2, const float* __restrict__ wuT3,
    const float* __restrict__ wuT4, const float* __restrict__ wuT5,
    const float* __restrict__ b0, const float* __restrict__ b1,
    const float* __restrict__ b2, const float* __restrict__ b3,
    const float* __restrict__ b4, const float* __restrict__ b5,
    float* __restrict__ dout, unsigned* __restrict__ f0,
    unsigned* __restrict__ f1, unsigned* __restrict__ f2,
    unsigned* __restrict__ f3, unsigned* __restrict__ f4,
    unsigned* __restrict__ f5, unsigned* __restrict__ eps) {
  __shared__ float wLDS[16 * 768];  // 48 KB: WG's 16 weight rows (max KT)
  __shared__ float sZ[4][16][64];   // 16 KB
  __shared__ float sH[256];         // 1 KB
  const int b = blockIdx.x;
  const int tid = threadIdx.x;
  // heavy layers (L0, L4) first so they land one-per-CU; aggregators last
  if (b < 128) {
    layer_body<256, 512, 128, false, false>(b, tid, xT, h0, wuT0, b0, nullptr,
                                            f0, eps + 0, nullptr, wLDS, sZ, sH);
  } else if (b < 256) {
    layer_body<256, 512, 128, false, true>(b - 128, tid, h3, h4, wuT4, b4,
                                           nullptr, f4, eps + 4, eps + 3, wLDS,
                                           sZ, sH);
  } else if (b < 320) {
    layer_body<512, 256, 64, false, true>(b - 256, tid, h0, h1, wuT1, b1,
                                          nullptr, f1, eps + 1, eps + 0, wLDS,
                                          sZ, sH);
  } else if (b < 384) {
    layer_body<64, 256, 64, false, true>(b - 320, tid, h2, h3, wuT3, b3,
                                         nullptr, f3, eps + 3, eps + 2, wLDS,
                                         sZ, sH);
  } else if (b < 448) {
    layer_body<512, 256, 64, true, true>(b - 384, tid, h4, h5, wuT5, b5, dout,
                                         f5, eps + 5, eps + 4, wLDS, sZ, sH);
  } else if (b < 464) {
    layer_body<256, 64, 16, false, true>(b - 448, tid, h1, h2, wuT2, b2,
                                         nullptr, f2, eps + 2, eps + 1, wLDS,
                                         sZ, sH);
  } else {
    const int l = b - 464;
    if (l == 0) agg_body<128>(f0, eps + 0);
    else if (l == 1) agg_body<64>(f1, eps + 1);
    else if (l == 2) agg_body<16>(f2, eps + 2);
    else if (l == 3) agg_body<64>(f3, eps + 3);
    else if (l == 4) agg_body<128>(f4, eps + 4);
    else agg_body<64>(f5, eps + 5);
  }
}

extern "C" void kernel_launch(void* const* d_in, const int* in_sizes, int n_in,
                              void* d_out, int out_size, void* d_ws,
                              size_t ws_size, hipStream_t stream) {
  (void)in_sizes; (void)n_in; (void)out_size; (void)ws_size;
  const float* x = (const float*)d_in[0];
  const float* W[6];
  const float* U[6];
  const float* B[6];
  for (int l = 0; l < 6; ++l) {
    W[l] = (const float*)d_in[1 + 3 * l];
    U[l] = (const float*)d_in[2 + 3 * l];
    B[l] = (const float*)d_in[3 + 3 * l];
  }
  char* ws = (char*)d_ws;
  // flags: [T][NWG] per layer; NWG = 128,64,16,64,128,64; then 6 epochs
  unsigned* f0 = (unsigned*)ws;
  unsigned* f1 = f0 + 128 * 256;
  unsigned* f2 = f1 + 64 * 256;
  unsigned* f3 = f2 + 16 * 256;
  unsigned* f4 = f3 + 64 * 256;
  unsigned* f5 = f4 + 128 * 256;
  unsigned* eps = f0 + 464 * 256;
  float* wuT0 = (float*)(ws + (1u << 20));
  float* wuT1 = wuT0 + (size_t)2048 * 768;
  float* wuT2 = wuT1 + (size_t)1024 * 768;
  float* wuT3 = wuT2 + (size_t)256 * 320;
  float* wuT4 = wuT3 + (size_t)1024 * 320;
  float* wuT5 = wuT4 + (size_t)2048 * 768;
  float* xT = (float*)(ws + (22u << 20));   // 16 MB
  float* h0 = (float*)(ws + (38u << 20));   // 32 MB
  float* h1 = (float*)(ws + (70u << 20));   // 16 MB
  float* h2 = (float*)(ws + (86u << 20));   // 4 MB
  float* h3 = (float*)(ws + (90u << 20));   // 16 MB
  float* h4 = (float*)(ws + (106u << 20));  // 32 MB
  float* h5 = (float*)(ws + (138u << 20));  // 16 MB (full T, no ring)

  hipMemsetAsync(f0, 0, (464 * 256 + 8) * sizeof(unsigned), stream);
  xpose_in<<<256, 256, 0, stream>>>(x, xT);
  pack_wu<<<dim3(32, 12), 256, 0, stream>>>(W[0], U[0], wuT0, 256, 512);
  pack_wu<<<dim3(16, 12), 256, 0, stream>>>(W[1], U[1], wuT1, 512, 256);
  pack_wu<<<dim3(4, 5), 256, 0, stream>>>(W[2], U[2], wuT2, 256, 64);
  pack_wu<<<dim3(16, 5), 256, 0, stream>>>(W[3], U[3], wuT3, 64, 256);
  pack_wu<<<dim3(32, 12), 256, 0, stream>>>(W[4], U[4], wuT4, 256, 512);
  pack_wu<<<dim3(16, 12), 256, 0, stream>>>(W[5], U[5], wuT5, 512, 256);

  lstm_fused<<<470, 256, 0, stream>>>(xT, h0, h1, h2, h3, h4, h5, wuT0, wuT1,
                                      wuT2, wuT3, wuT4, wuT5, B[0], B[1], B[2],
                                      B[3], B[4], B[5], (float*)d_out, f0, f1,
                                      f2, f3, f4, f5, eps);
}

// Round 12
// 5479.666 us; speedup vs baseline: 4.0905x; 1.0437x over previous
//
#include <hip/hip_runtime.h>
#include <stdint.h>

#define AGENT __HIP_MEMORY_SCOPE_AGENT
typedef unsigned long long u64;

// x[64][256][256] -> xT[t][iq][b][4]   (packed quads of input dim, batch-minor)
__global__ __launch_bounds__(256) void xpose_in(const float* __restrict__ x,
                                                float* __restrict__ xT) {
  const int t = blockIdx.x;
  const int b = threadIdx.x & 63;
  const int w = threadIdx.x >> 6;
  const float* xr = x + ((size_t)b * 256 + t) * 256;
  float* o = xT + (size_t)t * 64 * 256;
  for (int iq = w * 16; iq < w * 16 + 16; ++iq) {
    float4 v = *(const float4*)(xr + iq * 4);
    *(float4*)(o + ((size_t)iq * 64 + b) * 4) = v;
  }
}

// Pack [W;U] ([KT][4H], col cg) into wuT[cg][k] (transpose, coalesced both sides)
__global__ __launch_bounds__(256) void pack_wu(const float* __restrict__ W,
                                               const float* __restrict__ U,
                                               float* __restrict__ out,
                                               int DIN, int H) {
  __shared__ float tile[64][65];
  const int KT = DIN + H;
  const int c0 = blockIdx.x * 64;
  const int k0 = blockIdx.y * 64;
  const int tx = threadIdx.x & 63;
  const int ty = threadIdx.x >> 6;
  for (int r = ty; r < 64; r += 4) {
    const int k = k0 + r;
    tile[r][tx] = (k < DIN) ? W[(size_t)k * (4 * H) + c0 + tx]
                            : U[(size_t)(k - DIN) * (4 * H) + c0 + tx];
  }
  __syncthreads();
  for (int r = ty; r < 64; r += 4) {
    out[(size_t)(c0 + r) * KT + k0 + tx] = tile[tx][r];
  }
}

// Accumulate QW quads (this wave's K-slice) of src into acc[16] (c = g*4+jl).
// src: [quad][64][4]. Weights LDS-resident: wL[c*KT + k], wave-uniform
// ds_read_b128 broadcast. ANTI-SPILL + PIPELINE (round-11 lesson: the
// per-block sched_barrier(0) alone serializes ds->fma, 50% VALU duty):
// manual 2-deep weight double-buffer — each fenced region prefetches the
// NEXT cb-block's 4 float4s (parity cb&1) while fma'ing the CURRENT buffer,
// so fmas wait lgkmcnt(4) on block-old loads instead of lgkmcnt(0) on fresh
// ones. Live weight regs capped at 2 buffers (32 VGPRs).
template <int QW, int CH, int KT>
__device__ __forceinline__ void accum4L(const float* __restrict__ src, int q0,
                                        int kof0, const float* __restrict__ wL,
                                        int lane, float acc[16]) {
  constexpr int NCH = QW / CH;
  float4 cur[CH], nxt[CH];
  float4 wA[4], wB[4];
#pragma unroll
  for (int i = 0; i < CH; ++i)
    cur[i] = *(const float4*)(src + (size_t)(q0 + i) * 256 + lane * 4);
  // preload weight block (q0, cb=0) into wA
  {
    const int kof = kof0 + 4 * q0;
#pragma unroll
    for (int c = 0; c < 4; ++c)
      wA[c] = *(const float4*)(wL + (size_t)c * KT + kof);
  }
  for (int ch = 0; ch < NCH; ++ch) {
    const int qb = q0 + ch * CH;
    if (ch + 1 < NCH) {
#pragma unroll
      for (int i = 0; i < CH; ++i)
        nxt[i] = *(const float4*)(src + (size_t)(qb + CH + i) * 256 + lane * 4);
    }
#pragma unroll
    for (int i = 0; i < CH; ++i) {
      const int q = qb + i;
      const float4 xv = cur[i];
#pragma unroll
      for (int cb = 0; cb < 4; ++cb) {
        // prefetch next block: cb<3 -> (q, cb+1); cb==3 -> (q+1, 0).
        // Final overrun (last block of the call) reads 16B past this col's
        // rows — still inside the LDS block (lands in sZ), never consumed.
        const int cbn = (cb == 3) ? 0 : cb + 1;
        const int kofn = kof0 + 4 * ((cb == 3) ? q + 1 : q);
        if (cb & 1) {
#pragma unroll
          for (int c = 0; c < 4; ++c)
            wA[c] = *(const float4*)(wL + (size_t)(cbn * 4 + c) * KT + kofn);
        } else {
#pragma unroll
          for (int c = 0; c < 4; ++c)
            wB[c] = *(const float4*)(wL + (size_t)(cbn * 4 + c) * KT + kofn);
        }
        const float4 w0 = (cb & 1) ? wB[0] : wA[0];
        const float4 w1 = (cb & 1) ? wB[1] : wA[1];
        const float4 w2 = (cb & 1) ? wB[2] : wA[2];
        const float4 w3 = (cb & 1) ? wB[3] : wA[3];
        float& a0 = acc[cb * 4 + 0];
        float& a1 = acc[cb * 4 + 1];
        float& a2 = acc[cb * 4 + 2];
        float& a3 = acc[cb * 4 + 3];
        a0 = fmaf(w0.x, xv.x, a0); a0 = fmaf(w0.y, xv.y, a0);
        a0 = fmaf(w0.z, xv.z, a0); a0 = fmaf(w0.w, xv.w, a0);
        a1 = fmaf(w1.x, xv.x, a1); a1 = fmaf(w1.y, xv.y, a1);
        a1 = fmaf(w1.z, xv.z, a1); a1 = fmaf(w1.w, xv.w, a1);
        a2 = fmaf(w2.x, xv.x, a2); a2 = fmaf(w2.y, xv.y, a2);
        a2 = fmaf(w2.z, xv.z, a2); a2 = fmaf(w2.w, xv.w, a2);
        a3 = fmaf(w3.x, xv.x, a3); a3 = fmaf(w3.y, xv.y, a3);
        a3 = fmaf(w3.z, xv.z, a3); a3 = fmaf(w3.w, xv.w, a3);
        __builtin_amdgcn_sched_barrier(0);  // cap live weight regs (no spill)
      }
    }
#pragma unroll
    for (int i = 0; i < CH; ++i) cur[i] = nxt[i];
  }
}

// Dedicated per-layer aggregator: one wave gathers this layer's NWG per-WG
// flags for tick t, then publishes a single monotonic epoch word (= ticks
// completed). Consumers poll ONLY the epoch word (1 lane, 1 line).
template <int NWG>
__device__ __forceinline__ void agg_body(unsigned* __restrict__ flg,
                                         unsigned* __restrict__ ep) {
  const int tid = threadIdx.x;
  if (tid >= 64) return;  // single wave
  for (int t = 0; t < 256; ++t) {
    unsigned* base = flg + (size_t)t * NWG;
    if (NWG <= 64) {
      if (tid < NWG) {
        while (__hip_atomic_load(base + tid, __ATOMIC_RELAXED, AGENT) == 0u)
          __builtin_amdgcn_s_sleep(1);
      }
    } else {
      while (__hip_atomic_load(base + tid, __ATOMIC_RELAXED, AGENT) == 0u)
        __builtin_amdgcn_s_sleep(1);
      while (__hip_atomic_load(base + 64 + tid, __ATOMIC_RELAXED, AGENT) == 0u)
        __builtin_amdgcn_s_sleep(1);
    }
    asm volatile("s_waitcnt vmcnt(0)" ::: "memory");
    if (tid == 0)
      __hip_atomic_store(ep, (unsigned)(t + 1), __ATOMIC_RELAXED, AGENT);
  }
}

// One pipelined LSTM layer. 256-thread WG owns hidden quad wg (4 units);
// its 16 weight rows are staged ONCE into LDS. lane = batch; 4 waves split K
// 4-ways; wave jl owns unit jl's gates. Sync: per-WG flags -> aggregator ->
// epoch word; workers poll one word with one lane. Bulk h via cached loads.
template <int DIN, int H, int NWG, bool FIN, bool XCOH>
__device__ __forceinline__ void layer_body(
    int wg, int tid, const float* __restrict__ xin, float* __restrict__ hseq,
    const float* __restrict__ wuT, const float* __restrict__ bias,
    float* __restrict__ dout, unsigned* __restrict__ selfF,
    unsigned* __restrict__ selfE, unsigned* __restrict__ prevE,
    float* __restrict__ wL, float (*sZ)[16][64], float* sH) {
  constexpr int NQ2 = H / 4;
  constexpr int KT = DIN + H;
  constexpr int QW1 = DIN / 16;  // x-slice quads per wave
  constexpr int QW2 = H / 16;    // h-slice quads per wave
  constexpr int T = 256;
  static_assert(QW1 % 2 == 0 && QW2 % 2 == 0, "chunking assumes 2|QW");

  const int lane = tid & 63;
  const int wv = tid >> 6;  // 0..3

  // ---- stage this WG's 16 weight rows into LDS (once) ----
  {
    constexpr int R4 = KT / 4;  // float4s per row
    for (int i = tid; i < 16 * R4; i += 256) {
      const int row = i / R4;
      const int k4 = i - row * R4;
      const int grow = (row >> 2) * H + wg * 4 + (row & 3);  // c = g*4+jl
      *(float4*)&wL[(size_t)row * KT + 4 * k4] =
          *(const float4*)(wuT + (size_t)grow * KT + 4 * k4);
    }
  }
  float bz[4];
#pragma unroll
  for (int g = 0; g < 4; ++g) bz[g] = bias[g * H + wg * 4 + wv];
  float cst = 0.f;
  __syncthreads();

  for (int t = 0; t < T; ++t) {
    float acc[16];
#pragma unroll
    for (int c = 0; c < 16; ++c) acc[c] = 0.f;

    if (!XCOH) {
      // layer 0: x static — overlap input projection with waiting for peers
      accum4L<QW1, 2, KT>(xin + (size_t)t * (DIN / 4) * 256, wv * QW1, 0, wL,
                          lane, acc);
    }
    // single-lane epoch polls: tid 0 -> own layer (t-1 done); tid 64 -> prev
    if (t > 0 && tid == 0) {
      while (__hip_atomic_load(selfE, __ATOMIC_RELAXED, AGENT) < (unsigned)t)
        __builtin_amdgcn_s_sleep(2);
    }
    if (XCOH && tid == 64) {
      while (__hip_atomic_load(prevE, __ATOMIC_RELAXED, AGENT) <
             (unsigned)(t + 1))
        __builtin_amdgcn_s_sleep(2);
    }
    __syncthreads();
    asm volatile("" ::: "memory");  // no compiler hoist of loads above polls

    if (XCOH) {
      accum4L<QW1, 2, KT>(xin + (size_t)t * (DIN / 4) * 256, wv * QW1, 0, wL,
                          lane, acc);
    }
    if (t > 0) {
      accum4L<QW2, 2, KT>(hseq + (size_t)(t - 1) * NQ2 * 256, wv * QW2, DIN,
                          wL, lane, acc);
    }

    // 4-way K-split reduction
#pragma unroll
    for (int c = 0; c < 16; ++c) sZ[wv][c][lane] = acc[c];
    __syncthreads();

    float z[4];
#pragma unroll
    for (int g = 0; g < 4; ++g) {
      z[g] = bz[g];
#pragma unroll
      for (int k = 0; k < 4; ++k) z[g] += sZ[k][g * 4 + wv][lane];
    }
    const float ig = 1.f / (1.f + __expf(-z[0]));
    const float fg = 1.f / (1.f + __expf(-z[1]));
    const float gg = FIN ? tanhf(z[2]) : fmaxf(z[2], 0.f);
    const float og = 1.f / (1.f + __expf(-z[3]));
    cst = fg * cst + ig * gg;
    const float ca = FIN ? tanhf(cst) : fmaxf(cst, 0.f);
    const float h = og * ca;
    sH[lane * 4 + wv] = h;  // [b][jl]
    if (FIN && t == T - 1) dout[(size_t)lane * H + wg * 4 + wv] = h;
    __syncthreads();

    // wave 0 publishes the WG's 1 KB h-quad (agent write-through), then signal
    if (wv == 0) {
      const float4 v = *(const float4*)&sH[lane * 4];
      float* hw = hseq + (size_t)t * NQ2 * 256 + (size_t)wg * 256 + lane * 4;
      const u64 lo = ((u64)__float_as_uint(v.y) << 32) | __float_as_uint(v.x);
      const u64 hi = ((u64)__float_as_uint(v.w) << 32) | __float_as_uint(v.z);
      __hip_atomic_store((u64*)hw, lo, __ATOMIC_RELAXED, AGENT);
      __hip_atomic_store((u64*)hw + 1, hi, __ATOMIC_RELAXED, AGENT);
      asm volatile("s_waitcnt vmcnt(0)" ::: "memory");
      if (tid == 0)
        __hip_atomic_store(&selfF[t * NWG + wg], 1u, __ATOMIC_RELAXED, AGENT);
    }
  }
}

__global__ __launch_bounds__(256, 2) void lstm_fused(
    const float* __restrict__ xT, float* __restrict__ h0,
    float* __restrict__ h1, float* __restrict__ h2, float* __restrict__ h3,
    float* __restrict__ h4, float* __restrict__ h5,
    const float* __restrict__ wuT0, const float* __restrict__ wuT1,
    const float* __restrict__ wuT2, const float* __restrict__ wuT3,
    const float* __restrict__ wuT4, const float* __restrict__ wuT5,
    const float* __restrict__ b0, const float* __restrict__ b1,
    const float* __restrict__ b2, const float* __restrict__ b3,
    const float* __restrict__ b4, const float* __restrict__ b5,
    float* __restrict__ dout, unsigned* __restrict__ f0,
    unsigned* __restrict__ f1, unsigned* __restrict__ f2,
    unsigned* __restrict__ f3, unsigned* __restrict__ f4,
    unsigned* __restrict__ f5, unsigned* __restrict__ eps) {
  __shared__ float wLDS[16 * 768];  // 48 KB: WG's 16 weight rows (max KT)
  __shared__ float sZ[4][16][64];   // 16 KB
  __shared__ float sH[256];         // 1 KB
  const int b = blockIdx.x;
  const int tid = threadIdx.x;
  // heavy layers (L0, L4) first so they land one-per-CU; aggregators last
  if (b < 128) {
    layer_body<256, 512, 128, false, false>(b, tid, xT, h0, wuT0, b0, nullptr,
                                            f0, eps + 0, nullptr, wLDS, sZ, sH);
  } else if (b < 256) {
    layer_body<256, 512, 128, false, true>(b - 128, tid, h3, h4, wuT4, b4,
                                           nullptr, f4, eps + 4, eps + 3, wLDS,
                                           sZ, sH);
  } else if (b < 320) {
    layer_body<512, 256, 64, false, true>(b - 256, tid, h0, h1, wuT1, b1,
                                          nullptr, f1, eps + 1, eps + 0, wLDS,
                                          sZ, sH);
  } else if (b < 384) {
    layer_body<64, 256, 64, false, true>(b - 320, tid, h2, h3, wuT3, b3,
                                         nullptr, f3, eps + 3, eps + 2, wLDS,
                                         sZ, sH);
  } else if (b < 448) {
    layer_body<512, 256, 64, true, true>(b - 384, tid, h4, h5, wuT5, b5, dout,
                                         f5, eps + 5, eps + 4, wLDS, sZ, sH);
  } else if (b < 464) {
    layer_body<256, 64, 16, false, true>(b - 448, tid, h1, h2, wuT2, b2,
                                         nullptr, f2, eps + 2, eps + 1, wLDS,
                                         sZ, sH);
  } else {
    const int l = b - 464;
    if (l == 0) agg_body<128>(f0, eps + 0);
    else if (l == 1) agg_body<64>(f1, eps + 1);
    else if (l == 2) agg_body<16>(f2, eps + 2);
    else if (l == 3) agg_body<64>(f3, eps + 3);
    else if (l == 4) agg_body<128>(f4, eps + 4);
    else agg_body<64>(f5, eps + 5);
  }
}

extern "C" void kernel_launch(void* const* d_in, const int* in_sizes, int n_in,
                              void* d_out, int out_size, void* d_ws,
                              size_t ws_size, hipStream_t stream) {
  (void)in_sizes; (void)n_in; (void)out_size; (void)ws_size;
  const float* x = (const float*)d_in[0];
  const float* W[6];
  const float* U[6];
  const float* B[6];
  for (int l = 0; l < 6; ++l) {
    W[l] = (const float*)d_in[1 + 3 * l];
    U[l] = (const float*)d_in[2 + 3 * l];
    B[l] = (const float*)d_in[3 + 3 * l];
  }
  char* ws = (char*)d_ws;
  // flags: [T][NWG] per layer; NWG = 128,64,16,64,128,64; then 6 epochs
  unsigned* f0 = (unsigned*)ws;
  unsigned* f1 = f0 + 128 * 256;
  unsigned* f2 = f1 + 64 * 256;
  unsigned* f3 = f2 + 16 * 256;
  unsigned* f4 = f3 + 64 * 256;
  unsigned* f5 = f4 + 128 * 256;
  unsigned* eps = f0 + 464 * 256;
  float* wuT0 = (float*)(ws + (1u << 20));
  float* wuT1 = wuT0 + (size_t)2048 * 768;
  float* wuT2 = wuT1 + (size_t)1024 * 768;
  float* wuT3 = wuT2 + (size_t)256 * 320;
  float* wuT4 = wuT3 + (size_t)1024 * 320;
  float* wuT5 = wuT4 + (size_t)2048 * 768;
  float* xT = (float*)(ws + (22u << 20));   // 16 MB
  float* h0 = (float*)(ws + (38u << 20));   // 32 MB
  float* h1 = (float*)(ws + (70u << 20));   // 16 MB
  float* h2 = (float*)(ws + (86u << 20));   // 4 MB
  float* h3 = (float*)(ws + (90u << 20));   // 16 MB
  float* h4 = (float*)(ws + (106u << 20));  // 32 MB
  float* h5 = (float*)(ws + (138u << 20));  // 16 MB (full T, no ring)

  hipMemsetAsync(f0, 0, (464 * 256 + 8) * sizeof(unsigned), stream);
  xpose_in<<<256, 256, 0, stream>>>(x, xT);
  pack_wu<<<dim3(32, 12), 256, 0, stream>>>(W[0], U[0], wuT0, 256, 512);
  pack_wu<<<dim3(16, 12), 256, 0, stream>>>(W[1], U[1], wuT1, 512, 256);
  pack_wu<<<dim3(4, 5), 256, 0, stream>>>(W[2], U[2], wuT2, 256, 64);
  pack_wu<<<dim3(16, 5), 256, 0, stream>>>(W[3], U[3], wuT3, 64, 256);
  pack_wu<<<dim3(32, 12), 256, 0, stream>>>(W[4], U[4], wuT4, 256, 512);
  pack_wu<<<dim3(16, 12), 256, 0, stream>>>(W[5], U[5], wuT5, 512, 256);

  lstm_fused<<<470, 256, 0, stream>>>(xT, h0, h1, h2, h3, h4, h5, wuT0, wuT1,
                                      wuT2, wuT3, wuT4, wuT5, B[0], B[1], B[2],
                                      B[3], B[4], B[5], (float*)d_out, f0, f1,
                                      f2, f3, f4, f5, eps);
}